// Round 5
// baseline (158.660 us; speedup 1.0000x reference)
//
#include <hip/hip_runtime.h>
#include <hip/hip_bf16.h>

typedef __bf16 bf16x8 __attribute__((ext_vector_type(8)));
typedef float f32x4 __attribute__((ext_vector_type(4)));

#define N_NODE 50000
#define KPATH 8
#define LPATH 6
#define DNODE 64
#define DPATH 128
#define KDIM 320                 // DNODE*(LPATH-1)
#define N_EDGE 1600000
#define NPAIR (N_NODE * KPATH)   // 400000
#define M_BLK 32
#define NTILE (NPAIR / M_BLK)    // 12500
#define GRID 1024                // persistent: 4 blocks/CU on 256 CUs
#define ROW_BYTES 640            // 320 bf16 per row, swizzled
#define WF_BYTES 81920
#define FEATB_BYTES (N_NODE * DNODE * 2)
#define EWB_BYTES (N_EDGE * 2)

// XOR-swizzle: 16B unit moved within its 128B group by row. 640 = 5*128 so
// the XOR (max 112) never crosses a row boundary.
__device__ __forceinline__ int swz(int row, int bytecol) {
    return row * ROW_BYTES + (bytecol ^ ((row & 7) << 4));
}

// Pre-swizzle W (DPATH x KDIM, row-major f32) into bf16 MFMA B-fragment order:
// wf[((nt*10+ks)*64+lane)*8+j] = W[n=nt*16+(lane&15)][k=ks*32+(lane>>4)*8+j]
__global__ void wfrag_prep(const float* __restrict__ W, __bf16* __restrict__ wf) {
    int t = blockIdx.x * 256 + threadIdx.x;
    if (t >= 8 * 10 * 64 * 8) return;
    int j    = t & 7;
    int lane = (t >> 3) & 63;
    int ks   = (t >> 9) % 10;
    int nt   = t / 5120;
    int k = ks * 32 + (lane >> 4) * 8 + j;
    int n = nt * 16 + (lane & 15);
    wf[t] = (__bf16)W[n * KDIM + k];
}

// f32 -> bf16 bulk convert (each thread 8 elements)
__global__ void bf16_prep(const float* __restrict__ f, __bf16* __restrict__ fb, int n8) {
    int t = blockIdx.x * 256 + threadIdx.x;
    if (t >= n8) return;
    float4 a = ((const float4*)f)[t * 2];
    float4 b = ((const float4*)f)[t * 2 + 1];
    union { bf16x8 v; __bf16 e[8]; } u;
    u.e[0] = (__bf16)a.x; u.e[1] = (__bf16)a.y; u.e[2] = (__bf16)a.z; u.e[3] = (__bf16)a.w;
    u.e[4] = (__bf16)b.x; u.e[5] = (__bf16)b.y; u.e[6] = (__bf16)b.z; u.e[7] = (__bf16)b.w;
    ((bf16x8*)fb)[t] = u.v;
}

template <bool PREP>
__global__ __launch_bounds__(256, 4) void path_gemm(
    const void*  __restrict__ featv,
    const void*  __restrict__ weightv,
    const int*   __restrict__ paths,
    const int*   __restrict__ eids,
    const __bf16* __restrict__ wf,
    float* __restrict__ out)
{
    __shared__ bf16x8 AsVec[2][M_BLK * ROW_BYTES / 16];   // 2 x 20,480 B

    const int t    = threadIdx.x;
    const int wave = t >> 6;
    const int lane = t & 63;

    // ---- B fragments: resident in VGPRs for the whole kernel --------------
    bf16x8 breg[10][2];
#pragma unroll
    for (int ks = 0; ks < 10; ++ks)
#pragma unroll
        for (int nt = 0; nt < 2; ++nt)
            breg[ks][nt] = *(const bf16x8*)(wf + (((wave * 2 + nt) * 10 + ks) * 64 + lane) * 8);

    // staging geometry
    const int r  = t >> 3;           // row 0..31
    const int s  = t & 7;            // 16B slice
    const int d0 = s * 8;
    const int lr = (t >> 3) & 7;     // row-local within wave

    const int lrow = lane & 15;
    const int h    = lane >> 4;
    const int rbase = h * 4;

    int it = 0;
    for (int tile = blockIdx.x; tile < NTILE; tile += GRID, ++it) {
        char* asb = (char*)AsVec[it & 1];
        const long p0 = (long)tile * M_BLK;

        // ---------------- stage A tile: gather + combine -> bf16 LDS ------
        {
            const long p = p0 + r;
            int pv = 0;
            if (s < LPATH) pv = __builtin_nontemporal_load(paths + p * LPATH + s);
            float wv = 0.f;
            if (s < LPATH - 1) {
                int ev = __builtin_nontemporal_load(eids + p * (LPATH - 1) + s);
                wv = PREP ? (float)((const __bf16*)weightv)[ev]
                          : ((const float*)weightv)[ev];
            }

            int idx[LPATH];
#pragma unroll
            for (int l = 0; l < LPATH; ++l) idx[l] = __shfl(pv, lr * 8 + l, 64);
            float ew[LPATH - 1];
#pragma unroll
            for (int l = 0; l < LPATH - 1; ++l) ew[l] = __shfl(wv, lr * 8 + l, 64);

            float x[8];
#pragma unroll
            for (int l = 0; l < LPATH; ++l) {
                float y[8];
                const int id = idx[l];
                if (id >= N_NODE) {
#pragma unroll
                    for (int i = 0; i < 8; ++i) y[i] = 0.f;
                } else if (PREP) {
                    union { bf16x8 v; __bf16 e[8]; } u;
                    u.v = *(const bf16x8*)((const __bf16*)featv + (long)id * DNODE + d0);
#pragma unroll
                    for (int i = 0; i < 8; ++i) y[i] = (float)u.e[i];
                } else {
                    const float4* sp = (const float4*)((const float*)featv + (long)id * DNODE + d0);
                    *(float4*)&y[0] = sp[0];
                    *(float4*)&y[4] = sp[1];
                }
                if (l > 0) {
                    union { bf16x8 v; __bf16 e[8]; } u;
#pragma unroll
                    for (int i = 0; i < 8; ++i) u.e[i] = (__bf16)(x[i] + ew[l - 1] * y[i]);
                    *(bf16x8*)(asb + swz(r, (l - 1) * 128 + s * 16)) = u.v;
                }
#pragma unroll
                for (int i = 0; i < 8; ++i) x[i] = y[i];
            }
        }
        __syncthreads();
        // (next iteration's staging writes the OTHER buffer, so no trailing
        //  barrier is needed: the next __syncthreads orders reuse correctly)

        // ---------------- MFMA: wave computes 32 rows x 32 cols -----------
        f32x4 acc[2][2];
#pragma unroll
        for (int mt = 0; mt < 2; ++mt)
#pragma unroll
            for (int nt = 0; nt < 2; ++nt)
                acc[mt][nt] = (f32x4){0.f, 0.f, 0.f, 0.f};

#pragma unroll
        for (int ks = 0; ks < 10; ++ks) {
#pragma unroll
            for (int mt = 0; mt < 2; ++mt) {
                bf16x8 a = *(const bf16x8*)(asb + swz(mt * 16 + lrow, ks * 64 + h * 16));
                acc[mt][0] = __builtin_amdgcn_mfma_f32_16x16x32_bf16(a, breg[ks][0], acc[mt][0], 0, 0, 0);
                acc[mt][1] = __builtin_amdgcn_mfma_f32_16x16x32_bf16(a, breg[ks][1], acc[mt][1], 0, 0, 0);
            }
        }

        // ---------------- epilogue: non-temporal stores --------------------
#pragma unroll
        for (int mt = 0; mt < 2; ++mt) {
#pragma unroll
            for (int nt = 0; nt < 2; ++nt) {
#pragma unroll
                for (int q = 0; q < 4; ++q) {
                    long row = p0 + mt * 16 + rbase + q;
                    int  col = wave * 32 + nt * 16 + lrow;
                    __builtin_nontemporal_store(acc[mt][nt][q], &out[row * DPATH + col]);
                }
            }
        }
    }
}

extern "C" void kernel_launch(void* const* d_in, const int* in_sizes, int n_in,
                              void* d_out, int out_size, void* d_ws, size_t ws_size,
                              hipStream_t stream) {
    const float* feat   = (const float*)d_in[0];
    const float* weight = (const float*)d_in[1];
    const float* W      = (const float*)d_in[2];
    const int*   paths  = (const int*)d_in[3];
    const int*   eids   = (const int*)d_in[4];
    float* out = (float*)d_out;

    __bf16* wf    = (__bf16*)d_ws;                                   // 81,920 B
    __bf16* featb = (__bf16*)((char*)d_ws + WF_BYTES);               // 6,400,000 B
    __bf16* ewb   = (__bf16*)((char*)d_ws + WF_BYTES + FEATB_BYTES); // 3,200,000 B

    wfrag_prep<<<160, 256, 0, stream>>>(W, wf);

    if (ws_size >= (size_t)WF_BYTES + FEATB_BYTES + EWB_BYTES) {
        bf16_prep<<<(N_NODE * DNODE / 8 + 255) / 256, 256, 0, stream>>>(feat, featb, N_NODE * DNODE / 8);
        bf16_prep<<<(N_EDGE / 8 + 255) / 256, 256, 0, stream>>>(weight, ewb, N_EDGE / 8);
        path_gemm<true><<<GRID, 256, 0, stream>>>(featb, ewb, paths, eids, wf, out);
    } else {
        path_gemm<false><<<GRID, 256, 0, stream>>>(feat, weight, paths, eids, wf, out);
    }
}

// Round 6
// 123.815 us; speedup vs baseline: 1.2814x; 1.2814x over previous
//
#include <hip/hip_runtime.h>
#include <hip/hip_bf16.h>

typedef __bf16 bf16x8 __attribute__((ext_vector_type(8)));
typedef float f32x4 __attribute__((ext_vector_type(4)));

#define N_NODE 50000
#define KPATH 8
#define LPATH 6
#define DNODE 64
#define DPATH 128
#define KDIM 320                 // DNODE*(LPATH-1)
#define N_EDGE 1600000
#define NPAIR (N_NODE * KPATH)   // 400000
#define M_BLK 32
#define NBLK (NPAIR / M_BLK)     // 12500
#define ROW_BYTES 640            // 320 bf16 per row, swizzled
#define WF_BYTES 81920
#define FEATB_BYTES (N_NODE * DNODE * 2)
#define EWB_BYTES (N_EDGE * 2)

// XOR-swizzle: 16B unit moved within its 128B group by row. 640 = 5*128 so
// the XOR (max 112) never crosses a row boundary.
__device__ __forceinline__ int swz(int row, int bytecol) {
    return row * ROW_BYTES + (bytecol ^ ((row & 7) << 4));
}

// Pre-swizzle W (DPATH x KDIM, row-major f32) into bf16 MFMA B-fragment order:
// wf[((nt*10+ks)*64+lane)*8+j] = W[n=nt*16+(lane&15)][k=ks*32+(lane>>4)*8+j]
__global__ void wfrag_prep(const float* __restrict__ W, __bf16* __restrict__ wf) {
    int t = blockIdx.x * 256 + threadIdx.x;
    if (t >= 8 * 10 * 64 * 8) return;
    int j    = t & 7;
    int lane = (t >> 3) & 63;
    int ks   = (t >> 9) % 10;
    int nt   = t / 5120;
    int k = ks * 32 + (lane >> 4) * 8 + j;
    int n = nt * 16 + (lane & 15);
    wf[t] = (__bf16)W[n * KDIM + k];
}

// f32 -> bf16 bulk convert (each thread 8 elements)
__global__ void bf16_prep(const float* __restrict__ f, __bf16* __restrict__ fb, int n8) {
    int t = blockIdx.x * 256 + threadIdx.x;
    if (t >= n8) return;
    float4 a = ((const float4*)f)[t * 2];
    float4 b = ((const float4*)f)[t * 2 + 1];
    union { bf16x8 v; __bf16 e[8]; } u;
    u.e[0] = (__bf16)a.x; u.e[1] = (__bf16)a.y; u.e[2] = (__bf16)a.z; u.e[3] = (__bf16)a.w;
    u.e[4] = (__bf16)b.x; u.e[5] = (__bf16)b.y; u.e[6] = (__bf16)b.z; u.e[7] = (__bf16)b.w;
    ((bf16x8*)fb)[t] = u.v;
}

template <bool PREP>
__global__ __launch_bounds__(256) void path_gemm(
    const void*  __restrict__ featv,
    const void*  __restrict__ weightv,
    const int*   __restrict__ paths,
    const int*   __restrict__ eids,
    const __bf16* __restrict__ wf,
    float* __restrict__ out)
{
    __shared__ bf16x8 AsVec[M_BLK * ROW_BYTES / 16];   // 20,480 B -> 8 blocks/CU
    char* asb = (char*)AsVec;

    const int  t  = threadIdx.x;
    const long p0 = (long)blockIdx.x * M_BLK;

    // ---------------- stage A tile: gather + combine -> bf16 LDS ----------
    {
        const int  r  = t >> 3;          // row 0..31
        const int  s  = t & 7;           // 16B slice
        const int  d0 = s * 8;
        const int  lr = r & 7;           // row-local index within this wave
        const long p  = p0 + r;

        // Lane-split scalar gathers, broadcast to the row's 8 lanes.
        int pv = 0;
        if (s < LPATH) pv = __builtin_nontemporal_load(paths + p * LPATH + s);
        float wv = 0.f;
        if (s < LPATH - 1) {
            int ev = __builtin_nontemporal_load(eids + p * (LPATH - 1) + s);
            wv = PREP ? (float)((const __bf16*)weightv)[ev]
                      : ((const float*)weightv)[ev];
        }

        int idx[LPATH];
#pragma unroll
        for (int l = 0; l < LPATH; ++l) idx[l] = __shfl(pv, lr * 8 + l, 64);
        float ew[LPATH - 1];
#pragma unroll
        for (int l = 0; l < LPATH - 1; ++l) ew[l] = __shfl(wv, lr * 8 + l, 64);

        // Issue ALL 6 row-gathers unconditionally (clamped addr + mask) so
        // the misses overlap instead of serializing 6-deep.
        float msk[LPATH];
        union { bf16x8 v; __bf16 e[8]; } raw[LPATH];
        float4 rawf[LPATH][2];
#pragma unroll
        for (int l = 0; l < LPATH; ++l) {
            const int id = idx[l];
            msk[l] = (id < N_NODE) ? 1.f : 0.f;
            const long off = (long)(id < N_NODE ? id : 0) * DNODE + d0;
            if (PREP) {
                raw[l].v = *(const bf16x8*)((const __bf16*)featv + off);
            } else {
                const float4* sp = (const float4*)((const float*)featv + off);
                rawf[l][0] = sp[0];
                rawf[l][1] = sp[1];
            }
        }

        float x[8];
#pragma unroll
        for (int i = 0; i < 8; ++i)
            x[i] = PREP ? msk[0] * (float)raw[0].e[i]
                        : msk[0] * ((const float*)&rawf[0][0])[i];
#pragma unroll
        for (int l = 1; l < LPATH; ++l) {
            float y[8];
#pragma unroll
            for (int i = 0; i < 8; ++i)
                y[i] = PREP ? msk[l] * (float)raw[l].e[i]
                            : msk[l] * ((const float*)&rawf[l][0])[i];
            union { bf16x8 v; __bf16 e[8]; } u;
#pragma unroll
            for (int i = 0; i < 8; ++i) u.e[i] = (__bf16)(x[i] + ew[l - 1] * y[i]);
            *(bf16x8*)(asb + swz(r, (l - 1) * 128 + s * 16)) = u.v;
#pragma unroll
            for (int i = 0; i < 8; ++i) x[i] = y[i];
        }
    }
    __syncthreads();

    // ---------------- MFMA: each wave computes 32 rows x 32 cols ----------
    const int wave = t >> 6;
    const int lane = t & 63;
    const int lrow = lane & 15;
    const int h    = lane >> 4;

    f32x4 acc[2][2];
#pragma unroll
    for (int mt = 0; mt < 2; ++mt)
#pragma unroll
        for (int nt = 0; nt < 2; ++nt)
            acc[mt][nt] = (f32x4){0.f, 0.f, 0.f, 0.f};

#pragma unroll
    for (int ks = 0; ks < 10; ++ks) {
        bf16x8 b0 = *(const bf16x8*)(wf + (((wave * 2 + 0) * 10 + ks) * 64 + lane) * 8);
        bf16x8 b1 = *(const bf16x8*)(wf + (((wave * 2 + 1) * 10 + ks) * 64 + lane) * 8);
#pragma unroll
        for (int mt = 0; mt < 2; ++mt) {
            bf16x8 a = *(const bf16x8*)(asb + swz(mt * 16 + lrow, ks * 64 + h * 16));
            acc[mt][0] = __builtin_amdgcn_mfma_f32_16x16x32_bf16(a, b0, acc[mt][0], 0, 0, 0);
            acc[mt][1] = __builtin_amdgcn_mfma_f32_16x16x32_bf16(a, b1, acc[mt][1], 0, 0, 0);
        }
    }

    // ---------------- epilogue: non-temporal stores ------------------------
    const int rbase = h * 4;
#pragma unroll
    for (int mt = 0; mt < 2; ++mt) {
#pragma unroll
        for (int nt = 0; nt < 2; ++nt) {
#pragma unroll
            for (int q = 0; q < 4; ++q) {
                long row = p0 + mt * 16 + rbase + q;
                int  col = wave * 32 + nt * 16 + lrow;
                __builtin_nontemporal_store(acc[mt][nt][q], &out[row * DPATH + col]);
            }
        }
    }
}

extern "C" void kernel_launch(void* const* d_in, const int* in_sizes, int n_in,
                              void* d_out, int out_size, void* d_ws, size_t ws_size,
                              hipStream_t stream) {
    const float* feat   = (const float*)d_in[0];
    const float* weight = (const float*)d_in[1];
    const float* W      = (const float*)d_in[2];
    const int*   paths  = (const int*)d_in[3];
    const int*   eids   = (const int*)d_in[4];
    float* out = (float*)d_out;

    __bf16* wf    = (__bf16*)d_ws;                                   // 81,920 B
    __bf16* featb = (__bf16*)((char*)d_ws + WF_BYTES);               // 6,400,000 B
    __bf16* ewb   = (__bf16*)((char*)d_ws + WF_BYTES + FEATB_BYTES); // 3,200,000 B

    wfrag_prep<<<160, 256, 0, stream>>>(W, wf);

    if (ws_size >= (size_t)WF_BYTES + FEATB_BYTES + EWB_BYTES) {
        bf16_prep<<<(N_NODE * DNODE / 8 + 255) / 256, 256, 0, stream>>>(feat, featb, N_NODE * DNODE / 8);
        bf16_prep<<<(N_EDGE / 8 + 255) / 256, 256, 0, stream>>>(weight, ewb, N_EDGE / 8);
        path_gemm<true><<<NBLK, 256, 0, stream>>>(featb, ewb, paths, eids, wf, out);
    } else {
        path_gemm<false><<<NBLK, 256, 0, stream>>>(feat, weight, paths, eids, wf, out);
    }
}

// Round 7
// 123.766 us; speedup vs baseline: 1.2819x; 1.0004x over previous
//
#include <hip/hip_runtime.h>
#include <hip/hip_bf16.h>

typedef __bf16 bf16x8 __attribute__((ext_vector_type(8)));
typedef float f32x4 __attribute__((ext_vector_type(4)));

#define N_NODE 50000
#define KPATH 8
#define LPATH 6
#define DNODE 64
#define DPATH 128
#define KDIM 320                 // DNODE*(LPATH-1)
#define N_EDGE 1600000
#define NPAIR (N_NODE * KPATH)   // 400000
#define NEW (NPAIR * (LPATH - 1))// 2,000,000 path-edge slots
#define M_BLK 32
#define NBLK (NPAIR / M_BLK)     // 12500
#define ROW_BYTES 640            // 320 bf16 per row, swizzled
#define WF_BYTES 81920
#define FEATB_BYTES (N_NODE * DNODE * 2)
#define EWB_BYTES (N_EDGE * 2)
#define EWD_BYTES (NEW * 2)

// XOR-swizzle: 16B unit moved within its 128B group by row. 640 = 5*128 so
// the XOR (max 112) never crosses a row boundary.
__device__ __forceinline__ int swz(int row, int bytecol) {
    return row * ROW_BYTES + (bytecol ^ ((row & 7) << 4));
}

// Pre-swizzle W (DPATH x KDIM, row-major f32) into bf16 MFMA B-fragment order:
// wf[((nt*10+ks)*64+lane)*8+j] = W[n=nt*16+(lane&15)][k=ks*32+(lane>>4)*8+j]
__global__ void wfrag_prep(const float* __restrict__ W, __bf16* __restrict__ wf) {
    int t = blockIdx.x * 256 + threadIdx.x;
    if (t >= 8 * 10 * 64 * 8) return;
    int j    = t & 7;
    int lane = (t >> 3) & 63;
    int ks   = (t >> 9) % 10;
    int nt   = t / 5120;
    int k = ks * 32 + (lane >> 4) * 8 + j;
    int n = nt * 16 + (lane & 15);
    wf[t] = (__bf16)W[n * KDIM + k];
}

// f32 -> bf16 bulk convert (each thread 8 elements)
__global__ void bf16_prep(const float* __restrict__ f, __bf16* __restrict__ fb, int n8) {
    int t = blockIdx.x * 256 + threadIdx.x;
    if (t >= n8) return;
    float4 a = ((const float4*)f)[t * 2];
    float4 b = ((const float4*)f)[t * 2 + 1];
    union { bf16x8 v; __bf16 e[8]; } u;
    u.e[0] = (__bf16)a.x; u.e[1] = (__bf16)a.y; u.e[2] = (__bf16)a.z; u.e[3] = (__bf16)a.w;
    u.e[4] = (__bf16)b.x; u.e[5] = (__bf16)b.y; u.e[6] = (__bf16)b.z; u.e[7] = (__bf16)b.w;
    ((bf16x8*)fb)[t] = u.v;
}

// Pre-gather edge weights per path slot: ewd[t] = wsrc[eids[t]].
// With bf16 weight source (3.2 MB) the random gather fits per-XCD L2.
template <bool WBF16>
__global__ void ew_prep(const void* __restrict__ wsrc, const int* __restrict__ eids,
                        __bf16* __restrict__ ewd, int n) {
    int t = blockIdx.x * 256 + threadIdx.x;
    if (t >= n) return;
    int ev = __builtin_nontemporal_load(eids + t);
    float w = WBF16 ? (float)((const __bf16*)wsrc)[ev] : ((const float*)wsrc)[ev];
    ewd[t] = (__bf16)w;
}

// MODE: 2 = feat bf16 + pre-gathered ew ; 0 = all-f32 inline fallback
template <int MODE>
__global__ __launch_bounds__(256) void path_gemm(
    const void*  __restrict__ featv,
    const void*  __restrict__ wsrc,     // MODE2: ewd (dense bf16); MODE0: weight f32
    const int*   __restrict__ paths,
    const int*   __restrict__ eids,
    const __bf16* __restrict__ wf,
    float* __restrict__ out)
{
    __shared__ bf16x8 AsVec[M_BLK * ROW_BYTES / 16];   // 20,480 B -> 8 blocks/CU
    char* asb = (char*)AsVec;

    const int  t  = threadIdx.x;
    const long p0 = (long)blockIdx.x * M_BLK;

    // ---------------- stage A tile: gather + combine -> bf16 LDS ----------
    {
        const int  r  = t >> 3;          // row 0..31
        const int  s  = t & 7;           // 16B slice
        const int  d0 = s * 8;
        const int  lr = r & 7;           // row-local index within this wave
        const long p  = p0 + r;

        // Lane-split scalar loads, broadcast to the row's 8 lanes.
        int pv = 0;
        if (s < LPATH) pv = __builtin_nontemporal_load(paths + p * LPATH + s);
        float wv = 0.f;
        if (s < LPATH - 1) {
            if (MODE == 2) {
                // dense, coalesced-ish, streaming
                wv = (float)__builtin_nontemporal_load((const __bf16*)wsrc + p * (LPATH - 1) + s);
            } else {
                int ev = __builtin_nontemporal_load(eids + p * (LPATH - 1) + s);
                wv = ((const float*)wsrc)[ev];
            }
        }

        int idx[LPATH];
#pragma unroll
        for (int l = 0; l < LPATH; ++l) idx[l] = __shfl(pv, lr * 8 + l, 64);
        float ew[LPATH - 1];
#pragma unroll
        for (int l = 0; l < LPATH - 1; ++l) ew[l] = __shfl(wv, lr * 8 + l, 64);

        // Issue ALL 6 row-gathers unconditionally (clamped addr + mask) so
        // the misses overlap instead of serializing 6-deep.
        float msk[LPATH];
        union { bf16x8 v; __bf16 e[8]; } raw[LPATH];
        float4 rawf[LPATH][2];
#pragma unroll
        for (int l = 0; l < LPATH; ++l) {
            const int id = idx[l];
            msk[l] = (id < N_NODE) ? 1.f : 0.f;
            const long off = (long)(id < N_NODE ? id : 0) * DNODE + d0;
            if (MODE == 2) {
                raw[l].v = *(const bf16x8*)((const __bf16*)featv + off);
            } else {
                const float4* sp = (const float4*)((const float*)featv + off);
                rawf[l][0] = sp[0];
                rawf[l][1] = sp[1];
            }
        }

        float x[8];
#pragma unroll
        for (int i = 0; i < 8; ++i)
            x[i] = (MODE == 2) ? msk[0] * (float)raw[0].e[i]
                               : msk[0] * ((const float*)&rawf[0][0])[i];
#pragma unroll
        for (int l = 1; l < LPATH; ++l) {
            float y[8];
#pragma unroll
            for (int i = 0; i < 8; ++i)
                y[i] = (MODE == 2) ? msk[l] * (float)raw[l].e[i]
                                   : msk[l] * ((const float*)&rawf[l][0])[i];
            union { bf16x8 v; __bf16 e[8]; } u;
#pragma unroll
            for (int i = 0; i < 8; ++i) u.e[i] = (__bf16)(x[i] + ew[l - 1] * y[i]);
            *(bf16x8*)(asb + swz(r, (l - 1) * 128 + s * 16)) = u.v;
#pragma unroll
            for (int i = 0; i < 8; ++i) x[i] = y[i];
        }
    }
    __syncthreads();

    // ---------------- MFMA: each wave computes 32 rows x 32 cols ----------
    const int wave = t >> 6;
    const int lane = t & 63;
    const int lrow = lane & 15;
    const int h    = lane >> 4;

    f32x4 acc[2][2];
#pragma unroll
    for (int mt = 0; mt < 2; ++mt)
#pragma unroll
        for (int nt = 0; nt < 2; ++nt)
            acc[mt][nt] = (f32x4){0.f, 0.f, 0.f, 0.f};

#pragma unroll
    for (int ks = 0; ks < 10; ++ks) {
        bf16x8 b0 = *(const bf16x8*)(wf + (((wave * 2 + 0) * 10 + ks) * 64 + lane) * 8);
        bf16x8 b1 = *(const bf16x8*)(wf + (((wave * 2 + 1) * 10 + ks) * 64 + lane) * 8);
#pragma unroll
        for (int mt = 0; mt < 2; ++mt) {
            bf16x8 a = *(const bf16x8*)(asb + swz(mt * 16 + lrow, ks * 64 + h * 16));
            acc[mt][0] = __builtin_amdgcn_mfma_f32_16x16x32_bf16(a, b0, acc[mt][0], 0, 0, 0);
            acc[mt][1] = __builtin_amdgcn_mfma_f32_16x16x32_bf16(a, b1, acc[mt][1], 0, 0, 0);
        }
    }

    // ---------------- epilogue: non-temporal stores ------------------------
    const int rbase = h * 4;
#pragma unroll
    for (int mt = 0; mt < 2; ++mt) {
#pragma unroll
        for (int nt = 0; nt < 2; ++nt) {
#pragma unroll
            for (int q = 0; q < 4; ++q) {
                long row = p0 + mt * 16 + rbase + q;
                int  col = wave * 32 + nt * 16 + lrow;
                __builtin_nontemporal_store(acc[mt][nt][q], &out[row * DPATH + col]);
            }
        }
    }
}

extern "C" void kernel_launch(void* const* d_in, const int* in_sizes, int n_in,
                              void* d_out, int out_size, void* d_ws, size_t ws_size,
                              hipStream_t stream) {
    const float* feat   = (const float*)d_in[0];
    const float* weight = (const float*)d_in[1];
    const float* W      = (const float*)d_in[2];
    const int*   paths  = (const int*)d_in[3];
    const int*   eids   = (const int*)d_in[4];
    float* out = (float*)d_out;

    char* ws = (char*)d_ws;
    __bf16* wf    = (__bf16*)ws;                                   // 81,920 B
    __bf16* featb = (__bf16*)(ws + WF_BYTES);                      // 6,400,000 B
    __bf16* ewd   = (__bf16*)(ws + WF_BYTES + FEATB_BYTES);        // 4,000,000 B
    __bf16* ewb   = (__bf16*)(ws + WF_BYTES + FEATB_BYTES + EWD_BYTES); // 3,200,000 B

    wfrag_prep<<<160, 256, 0, stream>>>(W, wf);

    const size_t need_full = (size_t)WF_BYTES + FEATB_BYTES + EWD_BYTES + EWB_BYTES;
    const size_t need_mid  = (size_t)WF_BYTES + FEATB_BYTES + EWD_BYTES;

    if (ws_size >= need_full) {
        bf16_prep<<<(N_NODE * DNODE / 8 + 255) / 256, 256, 0, stream>>>(feat, featb, N_NODE * DNODE / 8);
        bf16_prep<<<(N_EDGE / 8 + 255) / 256, 256, 0, stream>>>(weight, ewb, N_EDGE / 8);
        ew_prep<true><<<(NEW + 255) / 256, 256, 0, stream>>>(ewb, eids, ewd, NEW);
        path_gemm<2><<<NBLK, 256, 0, stream>>>(featb, ewd, paths, eids, wf, out);
    } else if (ws_size >= need_mid) {
        bf16_prep<<<(N_NODE * DNODE / 8 + 255) / 256, 256, 0, stream>>>(feat, featb, N_NODE * DNODE / 8);
        ew_prep<false><<<(NEW + 255) / 256, 256, 0, stream>>>(weight, eids, ewd, NEW);
        path_gemm<2><<<NBLK, 256, 0, stream>>>(featb, ewd, paths, eids, wf, out);
    } else {
        path_gemm<0><<<NBLK, 256, 0, stream>>>(feat, weight, paths, eids, wf, out);
    }
}